// Round 3
// baseline (147.915 us; speedup 1.0000x reference)
//
#include <hip/hip_runtime.h>

#define TICKS 10000
#define NSYN 9
#define OUT_CH 64

#define SCATTER_BLOCKS 512          // 2 blocks/CU (80 KB LDS, 32/32 waves)
#define SCATTER_THREADS 1024

// ---------------------------------------------------------------------------
// Stage 0: zero the 9x10000 global histogram (ws is poisoned 0xAA each call).
// ---------------------------------------------------------------------------
__global__ void zero_kernel(float* __restrict__ p, int n) {
    int i = blockIdx.x * blockDim.x + threadIdx.x;
    if (i < n) p[i] = 0.0f;
}

// ---------------------------------------------------------------------------
// Stage 1: scatter events into the 9-class histogram.
// stride==1 fast path: class = min(y,2)*3 + min(x,2). ~97% of events are
// class 8 (x>=2 && y>=2) -> LDS-private per-block histogram (40 KB), flushed
// once at the end with coalesced, phase-staggered global atomics. Rare
// classes (~3%) go straight to global atomics (low contention).
// generic-stride path: direct 9-way global atomics.
// ---------------------------------------------------------------------------
__global__ __launch_bounds__(SCATTER_THREADS) void scatter_kernel(
    const float* __restrict__ values,
    const int*   __restrict__ ticks,
    const int*   __restrict__ xs,
    const int*   __restrict__ ys,
    const int*   __restrict__ stride_p,
    float*       __restrict__ hist,
    int n)
{
    __shared__ float lhist[TICKS];            // 40 KB: class-8 private hist
    const int stride = stride_p[0];           // wave-uniform
    const int tid = threadIdx.x;

    if (stride == 1) {
        for (int j = tid; j < TICKS; j += SCATTER_THREADS) lhist[j] = 0.0f;
        __syncthreads();

        const int n4  = n >> 2;
        const int gsz = gridDim.x * SCATTER_THREADS;
        const float4* __restrict__ v4 = (const float4*)values;
        const int4*   __restrict__ t4 = (const int4*)ticks;
        const int4*   __restrict__ x4 = (const int4*)xs;
        const int4*   __restrict__ y4 = (const int4*)ys;

        for (int i = blockIdx.x * SCATTER_THREADS + tid; i < n4; i += gsz) {
            float4 v = v4[i];
            int4   t = t4[i];
            int4   x = x4[i];
            int4   y = y4[i];

            if (x.x >= 2 && y.x >= 2) atomicAdd(&lhist[t.x], v.x);
            else atomicAdd(&hist[(min(y.x, 2) * 3 + min(x.x, 2)) * TICKS + t.x], v.x);

            if (x.y >= 2 && y.y >= 2) atomicAdd(&lhist[t.y], v.y);
            else atomicAdd(&hist[(min(y.y, 2) * 3 + min(x.y, 2)) * TICKS + t.y], v.y);

            if (x.z >= 2 && y.z >= 2) atomicAdd(&lhist[t.z], v.z);
            else atomicAdd(&hist[(min(y.z, 2) * 3 + min(x.z, 2)) * TICKS + t.z], v.z);

            if (x.w >= 2 && y.w >= 2) atomicAdd(&lhist[t.w], v.w);
            else atomicAdd(&hist[(min(y.w, 2) * 3 + min(x.w, 2)) * TICKS + t.w], v.w);
        }

        // scalar tail (n not multiple of 4): straight to global (atomic-safe)
        if ((n & 3) && blockIdx.x == 0 && tid == 0) {
            for (int i = n4 << 2; i < n; ++i) {
                atomicAdd(&hist[(min(ys[i], 2) * 3 + min(xs[i], 2)) * TICKS + ticks[i]],
                          values[i]);
            }
        }

        __syncthreads();

        // Flush class-8 LDS hist -> global, coalesced, phase-staggered so
        // blocks don't hit identical addresses in lockstep; skip empty bins.
        int phase = (blockIdx.x * 157) % TICKS;
        for (int j = tid; j < TICKS; j += SCATTER_THREADS) {
            int b = j + phase;
            if (b >= TICKS) b -= TICKS;
            float v = lhist[b];
            if (v != 0.0f) atomicAdd(&hist[8 * TICKS + b], v);
        }
    } else {
        const int gsz = gridDim.x * SCATTER_THREADS;
        for (int i = blockIdx.x * SCATTER_THREADS + tid; i < n; i += gsz) {
            float v = values[i];
            int   t = ticks[i];
            int   x = xs[i];
            int   y = ys[i];
            #pragma unroll
            for (int ky = 0; ky < 3; ++ky) {
                int oy = y - ky;
                if (oy < 0 || (oy % stride) != 0) continue;
                #pragma unroll
                for (int kx = 0; kx < 3; ++kx) {
                    int ox = x - kx;
                    if (ox < 0 || (ox % stride) != 0) continue;
                    atomicAdd(&hist[(ky * 3 + kx) * TICKS + t], v);
                }
            }
        }
    }
}

// ---------------------------------------------------------------------------
// Stage 2: suffix-sum the 3x3 classes (stride==1 only) and broadcast to all
// 64 channels. Thread owns tick column t. With gridDim.y == 1 (hist aliases
// out) one thread writes every channel; reads of column t happen before any
// write to column t, so aliasing is safe.
// ---------------------------------------------------------------------------
__global__ __launch_bounds__(256) void emit_kernel(
    const float* __restrict__ hist,
    const int*   __restrict__ stride_p,
    float*       __restrict__ out)
{
    int t = blockIdx.x * blockDim.x + threadIdx.x;
    if (t >= TICKS) return;
    const int stride = stride_p[0];

    float b[NSYN];
    #pragma unroll
    for (int s = 0; s < NSYN; ++s) b[s] = hist[s * TICKS + t];

    if (stride == 1) {
        // class hist h[cy][cx] -> buf[ky][kx] = sum_{cy>=ky, cx>=kx} h[cy][cx]
        #pragma unroll
        for (int r = 0; r < 3; ++r) {
            b[r * 3 + 1] += b[r * 3 + 2];
            b[r * 3 + 0] += b[r * 3 + 1];
        }
        #pragma unroll
        for (int c = 0; c < 3; ++c) {
            b[3 + c] += b[6 + c];
            b[0 + c] += b[3 + c];
        }
    }

    for (int c = blockIdx.y; c < OUT_CH; c += gridDim.y) {
        #pragma unroll
        for (int s = 0; s < NSYN; ++s) {
            out[(c * NSYN + s) * TICKS + t] = b[s];
        }
    }
}

// ---------------------------------------------------------------------------
extern "C" void kernel_launch(void* const* d_in, const int* in_sizes, int n_in,
                              void* d_out, int out_size, void* d_ws, size_t ws_size,
                              hipStream_t stream) {
    const float* values   = (const float*)d_in[0];
    const int*   ticks    = (const int*)  d_in[1];
    const int*   xs       = (const int*)  d_in[2];
    const int*   ys       = (const int*)  d_in[3];
    const int*   stride_p = (const int*)  d_in[4];
    float*       out      = (float*)      d_out;
    const int n = in_sizes[0];

    const size_t hist_bytes = (size_t)NSYN * TICKS * sizeof(float);
    float* hist;
    bool hist_in_out;
    if (ws_size >= hist_bytes) {
        hist = (float*)d_ws;
        hist_in_out = false;
    } else {
        hist = out;               // reuse channel-0 region of output as scratch
        hist_in_out = true;
    }

    // Stage 0: zero hist
    {
        int nh = NSYN * TICKS;
        zero_kernel<<<(nh + 255) / 256, 256, 0, stream>>>(hist, nh);
    }

    // Stage 1: scatter — 512 blocks x 1024 threads, 2 blocks/CU (80 KB LDS)
    scatter_kernel<<<SCATTER_BLOCKS, SCATTER_THREADS, 0, stream>>>(
        values, ticks, xs, ys, stride_p, hist, n);

    // Stage 2: suffix + 64-channel broadcast
    {
        dim3 grid((TICKS + 255) / 256, hist_in_out ? 1 : 64);
        emit_kernel<<<grid, 256, 0, stream>>>(hist, stride_p, out);
    }
}

// Round 4
// 146.731 us; speedup vs baseline: 1.0081x; 1.0081x over previous
//
#include <hip/hip_runtime.h>

#define TICKS 10000
#define NSYN 9
#define OUT_CH 64

#define NPART 32                    // partial flush rows (contention spreading)
#define SCATTER_BLOCKS 512          // 2 blocks/CU (80 KB LDS, 32/32 waves)
#define SCATTER_THREADS 1024

// ---------------------------------------------------------------------------
// Stage 0: zero buf[9][T] + part[NPART][T] (ws is poisoned 0xAA each call).
// ---------------------------------------------------------------------------
__global__ void zero_kernel(float* __restrict__ p, int n) {
    int i = blockIdx.x * blockDim.x + threadIdx.x;
    if (i < n) p[i] = 0.0f;
}

// ---------------------------------------------------------------------------
// Stage 1: scatter events.
// stride==1 fast path: ~97% of events are class 8 (x>=2 && y>=2) -> LDS
// private per-block histogram (40 KB), flushed to part[blockIdx % P] with
// coalesced, phase-staggered atomics (16 blocks/row -> low sector chains).
// Cold classes 0..7 (~3%) -> direct global atomics into buf rows (spread
// over 80000 addresses, negligible contention).
// generic-stride path: direct 9-way atomics into buf rows 0..8.
// ---------------------------------------------------------------------------
__global__ __launch_bounds__(SCATTER_THREADS) void scatter_kernel(
    const float* __restrict__ values,
    const int*   __restrict__ ticks,
    const int*   __restrict__ xs,
    const int*   __restrict__ ys,
    const int*   __restrict__ stride_p,
    float*       __restrict__ buf,     // [9][TICKS] cold classes (+all, generic)
    float*       __restrict__ part,    // [P][TICKS] hot-class partials
    int P,
    int n)
{
    __shared__ float lhist[TICKS];            // 40 KB: class-8 private hist
    const int stride = stride_p[0];           // wave-uniform
    const int tid = threadIdx.x;

    if (stride == 1) {
        for (int j = tid; j < TICKS; j += SCATTER_THREADS) lhist[j] = 0.0f;
        __syncthreads();

        const int n4  = n >> 2;
        const int gsz = gridDim.x * SCATTER_THREADS;
        const float4* __restrict__ v4 = (const float4*)values;
        const int4*   __restrict__ t4 = (const int4*)ticks;
        const int4*   __restrict__ x4 = (const int4*)xs;
        const int4*   __restrict__ y4 = (const int4*)ys;

        for (int i = blockIdx.x * SCATTER_THREADS + tid; i < n4; i += gsz) {
            float4 v = v4[i];
            int4   t = t4[i];
            int4   x = x4[i];
            int4   y = y4[i];

            if (x.x >= 2 && y.x >= 2) atomicAdd(&lhist[t.x], v.x);
            else atomicAdd(&buf[(min(y.x, 2) * 3 + min(x.x, 2)) * TICKS + t.x], v.x);

            if (x.y >= 2 && y.y >= 2) atomicAdd(&lhist[t.y], v.y);
            else atomicAdd(&buf[(min(y.y, 2) * 3 + min(x.y, 2)) * TICKS + t.y], v.y);

            if (x.z >= 2 && y.z >= 2) atomicAdd(&lhist[t.z], v.z);
            else atomicAdd(&buf[(min(y.z, 2) * 3 + min(x.z, 2)) * TICKS + t.z], v.z);

            if (x.w >= 2 && y.w >= 2) atomicAdd(&lhist[t.w], v.w);
            else atomicAdd(&buf[(min(y.w, 2) * 3 + min(x.w, 2)) * TICKS + t.w], v.w);
        }

        // scalar tail (n not multiple of 4): class 8 must go to a part row
        // (buf row 8 is ignored by combine when stride==1).
        if ((n & 3) && blockIdx.x == 0 && tid == 0) {
            for (int i = n4 << 2; i < n; ++i) {
                int cls = min(ys[i], 2) * 3 + min(xs[i], 2);
                if (cls == 8) atomicAdd(&part[ticks[i]], values[i]);
                else          atomicAdd(&buf[cls * TICKS + ticks[i]], values[i]);
            }
        }

        __syncthreads();

        // Flush LDS hist -> part[blockIdx % P], coalesced, phase-staggered
        // within each row group; skip empty bins.
        float* __restrict__ dst = part + (size_t)(blockIdx.x % P) * TICKS;
        int phase = ((blockIdx.x / P) * 613) % TICKS;
        for (int j = tid; j < TICKS; j += SCATTER_THREADS) {
            int b = j + phase;
            if (b >= TICKS) b -= TICKS;
            float v = lhist[b];
            if (v != 0.0f) atomicAdd(&dst[b], v);
        }
    } else {
        const int gsz = gridDim.x * SCATTER_THREADS;
        for (int i = blockIdx.x * SCATTER_THREADS + tid; i < n; i += gsz) {
            float v = values[i];
            int   t = ticks[i];
            int   x = xs[i];
            int   y = ys[i];
            #pragma unroll
            for (int ky = 0; ky < 3; ++ky) {
                int oy = y - ky;
                if (oy < 0 || (oy % stride) != 0) continue;
                #pragma unroll
                for (int kx = 0; kx < 3; ++kx) {
                    int ox = x - kx;
                    if (ox < 0 || (ox % stride) != 0) continue;
                    atomicAdd(&buf[(ky * 3 + kx) * TICKS + t], v);
                }
            }
        }
    }
}

// ---------------------------------------------------------------------------
// Stage 2a: combine partials + suffix-sum, in-place on buf.
// Thread t: b[8] = sum_p part[p][t] (stride==1), then 2D suffix over the 3x3
// classes; writes final buf[s][t]. Per-thread column-local -> in-place safe.
// ---------------------------------------------------------------------------
__global__ __launch_bounds__(256) void combine_kernel(
    float*       __restrict__ buf,
    const float* __restrict__ part,
    const int*   __restrict__ stride_p,
    int P)
{
    int t = blockIdx.x * blockDim.x + threadIdx.x;
    if (t >= TICKS) return;
    const int stride = stride_p[0];

    float b[NSYN];
    #pragma unroll
    for (int s = 0; s < NSYN; ++s) b[s] = buf[s * TICKS + t];

    if (stride == 1) {
        float s8 = 0.0f;
        for (int p = 0; p < P; ++p) s8 += part[(size_t)p * TICKS + t];
        b[8] = s8;
        // class hist h[cy][cx] -> buf[ky][kx] = sum_{cy>=ky, cx>=kx} h
        #pragma unroll
        for (int r = 0; r < 3; ++r) {
            b[r * 3 + 1] += b[r * 3 + 2];
            b[r * 3 + 0] += b[r * 3 + 1];
        }
        #pragma unroll
        for (int c = 0; c < 3; ++c) {
            b[3 + c] += b[6 + c];
            b[0 + c] += b[3 + c];
        }
    }

    #pragma unroll
    for (int s = 0; s < NSYN; ++s) buf[s * TICKS + t] = b[s];
}

// ---------------------------------------------------------------------------
// Stage 2b: broadcast buf[9][T] to all 64 channels, float4.
// Normal mode: grid (10, 64). Fallback (buf aliases out): grid (10, 1),
// thread reads its column before writing any channel -> alias-safe.
// ---------------------------------------------------------------------------
__global__ __launch_bounds__(256) void emit_kernel(
    const float* __restrict__ buf,
    float*       __restrict__ out)
{
    const int T4 = TICKS / 4;
    int t = blockIdx.x * blockDim.x + threadIdx.x;
    if (t >= T4) return;

    const float4* __restrict__ b4 = (const float4*)buf;
    float4*       __restrict__ o4 = (float4*)out;

    float4 b[NSYN];
    #pragma unroll
    for (int s = 0; s < NSYN; ++s) b[s] = b4[s * T4 + t];

    for (int c = blockIdx.y; c < OUT_CH; c += gridDim.y) {
        #pragma unroll
        for (int s = 0; s < NSYN; ++s) {
            o4[(c * NSYN + s) * T4 + t] = b[s];
        }
    }
}

// ---------------------------------------------------------------------------
extern "C" void kernel_launch(void* const* d_in, const int* in_sizes, int n_in,
                              void* d_out, int out_size, void* d_ws, size_t ws_size,
                              hipStream_t stream) {
    const float* values   = (const float*)d_in[0];
    const int*   ticks    = (const int*)  d_in[1];
    const int*   xs       = (const int*)  d_in[2];
    const int*   ys       = (const int*)  d_in[3];
    const int*   stride_p = (const int*)  d_in[4];
    float*       out      = (float*)      d_out;
    const int n = in_sizes[0];

    const size_t need = (size_t)(NSYN + NPART) * TICKS * sizeof(float);
    float* buf;
    float* part;
    int    P;
    bool   fallback;
    if (ws_size >= need) {
        buf = (float*)d_ws;
        part = buf + (size_t)NSYN * TICKS;
        P = NPART;
        fallback = false;
    } else {
        buf = out;                       // reuse channel-0 region of output
        part = buf + (size_t)8 * TICKS;  // part row 0 == buf row 8 (R1 scheme)
        P = 1;
        fallback = true;
    }

    // Stage 0: zero buf (+ part)
    {
        int nz = (fallback ? NSYN : (NSYN + NPART)) * TICKS;
        zero_kernel<<<(nz + 255) / 256, 256, 0, stream>>>(buf, nz);
    }

    // Stage 1: scatter
    scatter_kernel<<<SCATTER_BLOCKS, SCATTER_THREADS, 0, stream>>>(
        values, ticks, xs, ys, stride_p, buf, part, P, n);

    // Stage 2a: combine partials + suffix
    combine_kernel<<<(TICKS + 255) / 256, 256, 0, stream>>>(buf, part, stride_p, P);

    // Stage 2b: broadcast to 64 channels
    {
        dim3 grid((TICKS / 4 + 255) / 256, fallback ? 1 : 64);
        emit_kernel<<<grid, 256, 0, stream>>>(buf, out);
    }
}

// Round 5
// 135.580 us; speedup vs baseline: 1.0910x; 1.0822x over previous
//
#include <hip/hip_runtime.h>

#define TICKS 10000
#define NSYN 9
#define OUT_CH 64

#define SCATTER_BLOCKS 256          // one part row per block
#define SCATTER_THREADS 1024
#define COMBINE_BY 8                // parallel row-groups in combine

// ---------------------------------------------------------------------------
// Stage 0: zero buf[9][T] (ws is poisoned 0xAA each call). part needs no
// zeroing: scatter overwrites every part element with plain stores.
// ---------------------------------------------------------------------------
__global__ void zero_kernel(float* __restrict__ p, int n) {
    int i = blockIdx.x * blockDim.x + threadIdx.x;
    if (i < n) p[i] = 0.0f;
}

// ---------------------------------------------------------------------------
// Stage 1: scatter events.
// stride==1 fast path: ~97% of events are class 8 (x>=2 && y>=2) -> LDS
// private per-block histogram (40 KB). Flush:
//   P>0  : plain float4 stores of the whole row to part[blockIdx] (no atomics)
//   P==0 : fallback (tiny ws) — phase-staggered atomics into buf row 8 (R2)
// Cold classes 0..7 (~3%) -> direct global atomics into buf rows (spread over
// 80000 addresses, negligible contention).
// generic-stride path: direct 9-way atomics into buf rows 0..8 (part untouched).
// ---------------------------------------------------------------------------
__global__ __launch_bounds__(SCATTER_THREADS) void scatter_kernel(
    const float* __restrict__ values,
    const int*   __restrict__ ticks,
    const int*   __restrict__ xs,
    const int*   __restrict__ ys,
    const int*   __restrict__ stride_p,
    float*       __restrict__ buf,     // [9][TICKS]
    float*       __restrict__ part,    // [P][TICKS] hot-class private rows
    int P,
    int n)
{
    __shared__ float lhist[TICKS];            // 40 KB: class-8 private hist
    const int stride = stride_p[0];           // wave-uniform
    const int tid = threadIdx.x;

    if (stride == 1) {
        for (int j = tid; j < TICKS; j += SCATTER_THREADS) lhist[j] = 0.0f;
        __syncthreads();

        const int n4  = n >> 2;
        const int gsz = gridDim.x * SCATTER_THREADS;
        const float4* __restrict__ v4 = (const float4*)values;
        const int4*   __restrict__ t4 = (const int4*)ticks;
        const int4*   __restrict__ x4 = (const int4*)xs;
        const int4*   __restrict__ y4 = (const int4*)ys;

        for (int i = blockIdx.x * SCATTER_THREADS + tid; i < n4; i += gsz) {
            float4 v = v4[i];
            int4   t = t4[i];
            int4   x = x4[i];
            int4   y = y4[i];

            if (x.x >= 2 && y.x >= 2) atomicAdd(&lhist[t.x], v.x);
            else atomicAdd(&buf[(min(y.x, 2) * 3 + min(x.x, 2)) * TICKS + t.x], v.x);

            if (x.y >= 2 && y.y >= 2) atomicAdd(&lhist[t.y], v.y);
            else atomicAdd(&buf[(min(y.y, 2) * 3 + min(x.y, 2)) * TICKS + t.y], v.y);

            if (x.z >= 2 && y.z >= 2) atomicAdd(&lhist[t.z], v.z);
            else atomicAdd(&buf[(min(y.z, 2) * 3 + min(x.z, 2)) * TICKS + t.z], v.z);

            if (x.w >= 2 && y.w >= 2) atomicAdd(&lhist[t.w], v.w);
            else atomicAdd(&buf[(min(y.w, 2) * 3 + min(x.w, 2)) * TICKS + t.w], v.w);
        }

        // scalar tail (n not multiple of 4): class 8 -> buf row 8 directly
        // (combine ADDS part sums on top, so this is preserved).
        if ((n & 3) && blockIdx.x == 0 && tid == 0) {
            for (int i = n4 << 2; i < n; ++i) {
                int cls = min(ys[i], 2) * 3 + min(xs[i], 2);
                atomicAdd(&buf[cls * TICKS + ticks[i]], values[i]);
            }
        }

        __syncthreads();

        if (P > 0) {
            // Plain coalesced float4 store of the entire private row.
            const float4* __restrict__ l4 = (const float4*)lhist;
            float4* __restrict__ dst = (float4*)(part + (size_t)blockIdx.x * TICKS);
            const int T4 = TICKS / 4;
            for (int j = tid; j < T4; j += SCATTER_THREADS) dst[j] = l4[j];
        } else {
            // Fallback: phase-staggered atomics into buf row 8, skip zeros.
            int phase = (blockIdx.x * 157) % TICKS;
            for (int j = tid; j < TICKS; j += SCATTER_THREADS) {
                int b = j + phase;
                if (b >= TICKS) b -= TICKS;
                float v = lhist[b];
                if (v != 0.0f) atomicAdd(&buf[8 * TICKS + b], v);
            }
        }
    } else {
        const int gsz = gridDim.x * SCATTER_THREADS;
        for (int i = blockIdx.x * SCATTER_THREADS + tid; i < n; i += gsz) {
            float v = values[i];
            int   t = ticks[i];
            int   x = xs[i];
            int   y = ys[i];
            #pragma unroll
            for (int ky = 0; ky < 3; ++ky) {
                int oy = y - ky;
                if (oy < 0 || (oy % stride) != 0) continue;
                #pragma unroll
                for (int kx = 0; kx < 3; ++kx) {
                    int ox = x - kx;
                    if (ox < 0 || (ox % stride) != 0) continue;
                    atomicAdd(&buf[(ky * 3 + kx) * TICKS + t], v);
                }
            }
        }
    }
}

// ---------------------------------------------------------------------------
// Stage 2a: reduce part[P][T] into buf row 8. Grid (T4/256, COMBINE_BY);
// block (bx, by) sums rows [by*P/BY, (by+1)*P/BY) for its tick chunk and
// atomicAdds into buf[8] (COMBINE_BY collisions/address — negligible).
// Only meaningful when stride==1 and P>0; early-out otherwise (part is
// uninitialized poison in the generic-stride path).
// ---------------------------------------------------------------------------
__global__ __launch_bounds__(256) void combine_kernel(
    float*       __restrict__ buf,
    const float* __restrict__ part,
    const int*   __restrict__ stride_p,
    int P)
{
    if (stride_p[0] != 1 || P <= 0) return;
    const int T4 = TICKS / 4;
    int t4 = blockIdx.x * blockDim.x + threadIdx.x;
    if (t4 >= T4) return;

    const int rows = P / COMBINE_BY;
    const int r0   = blockIdx.y * rows;
    const float4* __restrict__ p4 = (const float4*)part;

    float4 s = make_float4(0.f, 0.f, 0.f, 0.f);
    for (int r = r0; r < r0 + rows; ++r) {
        float4 v = p4[(size_t)r * T4 + t4];
        s.x += v.x; s.y += v.y; s.z += v.z; s.w += v.w;
    }
    float* dst = buf + 8 * TICKS + 4 * t4;
    atomicAdd(dst + 0, s.x);
    atomicAdd(dst + 1, s.y);
    atomicAdd(dst + 2, s.z);
    atomicAdd(dst + 3, s.w);
}

// ---------------------------------------------------------------------------
// Stage 2b: suffix-sum the 3x3 classes (stride==1 only) + broadcast to all
// 64 channels, float4. Fallback (buf aliases out): grid (.,1); each float4
// column is read by exactly the thread that writes it -> alias-safe.
// ---------------------------------------------------------------------------
__global__ __launch_bounds__(256) void emit_kernel(
    const float* __restrict__ buf,
    const int*   __restrict__ stride_p,
    float*       __restrict__ out)
{
    const int T4 = TICKS / 4;
    int t = blockIdx.x * blockDim.x + threadIdx.x;
    if (t >= T4) return;
    const int stride = stride_p[0];

    const float4* __restrict__ b4 = (const float4*)buf;
    float4*       __restrict__ o4 = (float4*)out;

    float4 b[NSYN];
    #pragma unroll
    for (int s = 0; s < NSYN; ++s) b[s] = b4[s * T4 + t];

    if (stride == 1) {
        // class hist h[cy][cx] -> buf[ky][kx] = sum_{cy>=ky, cx>=kx} h
        #pragma unroll
        for (int r = 0; r < 3; ++r) {
            int i2 = r * 3 + 2, i1 = r * 3 + 1, i0 = r * 3;
            b[i1].x += b[i2].x; b[i1].y += b[i2].y; b[i1].z += b[i2].z; b[i1].w += b[i2].w;
            b[i0].x += b[i1].x; b[i0].y += b[i1].y; b[i0].z += b[i1].z; b[i0].w += b[i1].w;
        }
        #pragma unroll
        for (int c = 0; c < 3; ++c) {
            b[3 + c].x += b[6 + c].x; b[3 + c].y += b[6 + c].y;
            b[3 + c].z += b[6 + c].z; b[3 + c].w += b[6 + c].w;
            b[0 + c].x += b[3 + c].x; b[0 + c].y += b[3 + c].y;
            b[0 + c].z += b[3 + c].z; b[0 + c].w += b[3 + c].w;
        }
    }

    for (int c = blockIdx.y; c < OUT_CH; c += gridDim.y) {
        #pragma unroll
        for (int s = 0; s < NSYN; ++s) {
            o4[(c * NSYN + s) * T4 + t] = b[s];
        }
    }
}

// ---------------------------------------------------------------------------
extern "C" void kernel_launch(void* const* d_in, const int* in_sizes, int n_in,
                              void* d_out, int out_size, void* d_ws, size_t ws_size,
                              hipStream_t stream) {
    const float* values   = (const float*)d_in[0];
    const int*   ticks    = (const int*)  d_in[1];
    const int*   xs       = (const int*)  d_in[2];
    const int*   ys       = (const int*)  d_in[3];
    const int*   stride_p = (const int*)  d_in[4];
    float*       out      = (float*)      d_out;
    const int n = in_sizes[0];

    const size_t need = (size_t)(NSYN + SCATTER_BLOCKS) * TICKS * sizeof(float);
    float* buf;
    float* part;
    int    P;
    bool   fallback;
    if (ws_size >= need) {
        buf = (float*)d_ws;
        part = buf + (size_t)NSYN * TICKS;
        P = SCATTER_BLOCKS;
        fallback = false;
    } else {
        buf = out;                       // reuse channel-0 region of output
        part = buf;                      // unused (P==0 -> atomic flush path)
        P = 0;
        fallback = true;
    }

    // Stage 0: zero buf
    {
        int nz = NSYN * TICKS;
        zero_kernel<<<(nz + 255) / 256, 256, 0, stream>>>(buf, nz);
    }

    // Stage 1: scatter — grid must equal P when P>0 (one part row per block)
    scatter_kernel<<<SCATTER_BLOCKS, SCATTER_THREADS, 0, stream>>>(
        values, ticks, xs, ys, stride_p, buf, part, P, n);

    // Stage 2a: reduce part rows into buf row 8 (no-op when P==0 or stride!=1)
    {
        dim3 grid((TICKS / 4 + 255) / 256, COMBINE_BY);
        combine_kernel<<<grid, 256, 0, stream>>>(buf, part, stride_p, P);
    }

    // Stage 2b: suffix + broadcast to 64 channels
    {
        dim3 grid((TICKS / 4 + 255) / 256, fallback ? 1 : 64);
        emit_kernel<<<grid, 256, 0, stream>>>(buf, stride_p, out);
    }
}

// Round 6
// 135.019 us; speedup vs baseline: 1.0955x; 1.0042x over previous
//
#include <hip/hip_runtime.h>

#define TICKS 10000
#define NSYN 9
#define OUT_CH 64

#define SCATTER_BLOCKS 256          // one part row per block
#define SCATTER_THREADS 1024
#define COMBINE_BY 8                // parallel row-groups in combine

// Hardware fp32 atomic add (ds_add_f32 / global_atomic_add_f32), not the
// CAS retry loop plain atomicAdd(float*) can lower to. Values here are exact
// small integers -> associativity/rounding is a non-issue.
__device__ __forceinline__ void hw_atomic_add(float* p, float v) {
    unsafeAtomicAdd(p, v);
}

// ---------------------------------------------------------------------------
// Stage 0: zero buf[9][T] (ws is poisoned 0xAA each call). part needs no
// zeroing: scatter overwrites every part element with plain stores.
// ---------------------------------------------------------------------------
__global__ void zero_kernel(float* __restrict__ p, int n) {
    int i = blockIdx.x * blockDim.x + threadIdx.x;
    if (i < n) p[i] = 0.0f;
}

// ---------------------------------------------------------------------------
// Stage 1: scatter events.
// stride==1 fast path: ~97% of events are class 8 (x>=2 && y>=2) -> LDS
// private per-block histogram (40 KB, ds_add_f32). Flush:
//   P>0  : plain float4 stores of the whole row to part[blockIdx] (no atomics)
//   P==0 : fallback (tiny ws) — phase-staggered atomics into buf row 8
// Cold classes 0..7 (~3%) -> direct global HW atomics into buf rows.
// generic-stride path: direct 9-way atomics into buf rows 0..8 (part untouched).
// ---------------------------------------------------------------------------
__global__ __launch_bounds__(SCATTER_THREADS) void scatter_kernel(
    const float* __restrict__ values,
    const int*   __restrict__ ticks,
    const int*   __restrict__ xs,
    const int*   __restrict__ ys,
    const int*   __restrict__ stride_p,
    float*       __restrict__ buf,     // [9][TICKS]
    float*       __restrict__ part,    // [P][TICKS] hot-class private rows
    int P,
    int n)
{
    __shared__ float lhist[TICKS];            // 40 KB: class-8 private hist
    const int stride = stride_p[0];           // wave-uniform
    const int tid = threadIdx.x;

    if (stride == 1) {
        for (int j = tid; j < TICKS; j += SCATTER_THREADS) lhist[j] = 0.0f;
        __syncthreads();

        const int n4  = n >> 2;
        const int gsz = gridDim.x * SCATTER_THREADS;
        const float4* __restrict__ v4 = (const float4*)values;
        const int4*   __restrict__ t4 = (const int4*)ticks;
        const int4*   __restrict__ x4 = (const int4*)xs;
        const int4*   __restrict__ y4 = (const int4*)ys;

        for (int i = blockIdx.x * SCATTER_THREADS + tid; i < n4; i += gsz) {
            float4 v = v4[i];
            int4   t = t4[i];
            int4   x = x4[i];
            int4   y = y4[i];

            if (x.x >= 2 && y.x >= 2) hw_atomic_add(&lhist[t.x], v.x);
            else hw_atomic_add(&buf[(min(y.x, 2) * 3 + min(x.x, 2)) * TICKS + t.x], v.x);

            if (x.y >= 2 && y.y >= 2) hw_atomic_add(&lhist[t.y], v.y);
            else hw_atomic_add(&buf[(min(y.y, 2) * 3 + min(x.y, 2)) * TICKS + t.y], v.y);

            if (x.z >= 2 && y.z >= 2) hw_atomic_add(&lhist[t.z], v.z);
            else hw_atomic_add(&buf[(min(y.z, 2) * 3 + min(x.z, 2)) * TICKS + t.z], v.z);

            if (x.w >= 2 && y.w >= 2) hw_atomic_add(&lhist[t.w], v.w);
            else hw_atomic_add(&buf[(min(y.w, 2) * 3 + min(x.w, 2)) * TICKS + t.w], v.w);
        }

        // scalar tail (n not multiple of 4): class 8 -> buf row 8 directly
        // (combine ADDS part sums on top, so this is preserved).
        if ((n & 3) && blockIdx.x == 0 && tid == 0) {
            for (int i = n4 << 2; i < n; ++i) {
                int cls = min(ys[i], 2) * 3 + min(xs[i], 2);
                hw_atomic_add(&buf[cls * TICKS + ticks[i]], values[i]);
            }
        }

        __syncthreads();

        if (P > 0) {
            // Plain coalesced float4 store of the entire private row.
            const float4* __restrict__ l4 = (const float4*)lhist;
            float4* __restrict__ dst = (float4*)(part + (size_t)blockIdx.x * TICKS);
            const int T4 = TICKS / 4;
            for (int j = tid; j < T4; j += SCATTER_THREADS) dst[j] = l4[j];
        } else {
            // Fallback: phase-staggered atomics into buf row 8, skip zeros.
            int phase = (blockIdx.x * 157) % TICKS;
            for (int j = tid; j < TICKS; j += SCATTER_THREADS) {
                int b = j + phase;
                if (b >= TICKS) b -= TICKS;
                float v = lhist[b];
                if (v != 0.0f) hw_atomic_add(&buf[8 * TICKS + b], v);
            }
        }
    } else {
        const int gsz = gridDim.x * SCATTER_THREADS;
        for (int i = blockIdx.x * SCATTER_THREADS + tid; i < n; i += gsz) {
            float v = values[i];
            int   t = ticks[i];
            int   x = xs[i];
            int   y = ys[i];
            #pragma unroll
            for (int ky = 0; ky < 3; ++ky) {
                int oy = y - ky;
                if (oy < 0 || (oy % stride) != 0) continue;
                #pragma unroll
                for (int kx = 0; kx < 3; ++kx) {
                    int ox = x - kx;
                    if (ox < 0 || (ox % stride) != 0) continue;
                    hw_atomic_add(&buf[(ky * 3 + kx) * TICKS + t], v);
                }
            }
        }
    }
}

// ---------------------------------------------------------------------------
// Stage 2a: reduce part[P][T] into buf row 8. Grid (T4/256, COMBINE_BY);
// block (bx, by) sums rows [by*P/BY, (by+1)*P/BY) for its tick chunk and
// HW-atomicAdds into buf[8] (COMBINE_BY collisions/address — negligible).
// Early-out when stride!=1 or P==0 (part is uninitialized in those paths).
// ---------------------------------------------------------------------------
__global__ __launch_bounds__(256) void combine_kernel(
    float*       __restrict__ buf,
    const float* __restrict__ part,
    const int*   __restrict__ stride_p,
    int P)
{
    if (stride_p[0] != 1 || P <= 0) return;
    const int T4 = TICKS / 4;
    int t4 = blockIdx.x * blockDim.x + threadIdx.x;
    if (t4 >= T4) return;

    const int rows = P / COMBINE_BY;
    const int r0   = blockIdx.y * rows;
    const float4* __restrict__ p4 = (const float4*)part;

    float4 s = make_float4(0.f, 0.f, 0.f, 0.f);
    for (int r = r0; r < r0 + rows; ++r) {
        float4 v = p4[(size_t)r * T4 + t4];
        s.x += v.x; s.y += v.y; s.z += v.z; s.w += v.w;
    }
    float* dst = buf + 8 * TICKS + 4 * t4;
    hw_atomic_add(dst + 0, s.x);
    hw_atomic_add(dst + 1, s.y);
    hw_atomic_add(dst + 2, s.z);
    hw_atomic_add(dst + 3, s.w);
}

// ---------------------------------------------------------------------------
// Stage 2b: suffix-sum the 3x3 classes (stride==1 only) + broadcast to all
// 64 channels, float4. Fallback (buf aliases out): grid (.,1); each float4
// column is read by exactly the thread that writes it -> alias-safe.
// ---------------------------------------------------------------------------
__global__ __launch_bounds__(256) void emit_kernel(
    const float* __restrict__ buf,
    const int*   __restrict__ stride_p,
    float*       __restrict__ out)
{
    const int T4 = TICKS / 4;
    int t = blockIdx.x * blockDim.x + threadIdx.x;
    if (t >= T4) return;
    const int stride = stride_p[0];

    const float4* __restrict__ b4 = (const float4*)buf;
    float4*       __restrict__ o4 = (float4*)out;

    float4 b[NSYN];
    #pragma unroll
    for (int s = 0; s < NSYN; ++s) b[s] = b4[s * T4 + t];

    if (stride == 1) {
        // class hist h[cy][cx] -> buf[ky][kx] = sum_{cy>=ky, cx>=kx} h
        #pragma unroll
        for (int r = 0; r < 3; ++r) {
            int i2 = r * 3 + 2, i1 = r * 3 + 1, i0 = r * 3;
            b[i1].x += b[i2].x; b[i1].y += b[i2].y; b[i1].z += b[i2].z; b[i1].w += b[i2].w;
            b[i0].x += b[i1].x; b[i0].y += b[i1].y; b[i0].z += b[i1].z; b[i0].w += b[i1].w;
        }
        #pragma unroll
        for (int c = 0; c < 3; ++c) {
            b[3 + c].x += b[6 + c].x; b[3 + c].y += b[6 + c].y;
            b[3 + c].z += b[6 + c].z; b[3 + c].w += b[6 + c].w;
            b[0 + c].x += b[3 + c].x; b[0 + c].y += b[3 + c].y;
            b[0 + c].z += b[3 + c].z; b[0 + c].w += b[3 + c].w;
        }
    }

    for (int c = blockIdx.y; c < OUT_CH; c += gridDim.y) {
        #pragma unroll
        for (int s = 0; s < NSYN; ++s) {
            o4[(c * NSYN + s) * T4 + t] = b[s];
        }
    }
}

// ---------------------------------------------------------------------------
extern "C" void kernel_launch(void* const* d_in, const int* in_sizes, int n_in,
                              void* d_out, int out_size, void* d_ws, size_t ws_size,
                              hipStream_t stream) {
    const float* values   = (const float*)d_in[0];
    const int*   ticks    = (const int*)  d_in[1];
    const int*   xs       = (const int*)  d_in[2];
    const int*   ys       = (const int*)  d_in[3];
    const int*   stride_p = (const int*)  d_in[4];
    float*       out      = (float*)      d_out;
    const int n = in_sizes[0];

    const size_t need = (size_t)(NSYN + SCATTER_BLOCKS) * TICKS * sizeof(float);
    float* buf;
    float* part;
    int    P;
    bool   fallback;
    if (ws_size >= need) {
        buf = (float*)d_ws;
        part = buf + (size_t)NSYN * TICKS;
        P = SCATTER_BLOCKS;
        fallback = false;
    } else {
        buf = out;                       // reuse channel-0 region of output
        part = buf;                      // unused (P==0 -> atomic flush path)
        P = 0;
        fallback = true;
    }

    // Stage 0: zero buf
    {
        int nz = NSYN * TICKS;
        zero_kernel<<<(nz + 255) / 256, 256, 0, stream>>>(buf, nz);
    }

    // Stage 1: scatter — grid must equal P when P>0 (one part row per block)
    scatter_kernel<<<SCATTER_BLOCKS, SCATTER_THREADS, 0, stream>>>(
        values, ticks, xs, ys, stride_p, buf, part, P, n);

    // Stage 2a: reduce part rows into buf row 8 (no-op when P==0 or stride!=1)
    {
        dim3 grid((TICKS / 4 + 255) / 256, COMBINE_BY);
        combine_kernel<<<grid, 256, 0, stream>>>(buf, part, stride_p, P);
    }

    // Stage 2b: suffix + broadcast to 64 channels
    {
        dim3 grid((TICKS / 4 + 255) / 256, fallback ? 1 : 64);
        emit_kernel<<<grid, 256, 0, stream>>>(buf, stride_p, out);
    }
}